// Round 9
// baseline (363.469 us; speedup 1.0000x reference)
//
#include <hip/hip_runtime.h>

// LSTM: B=2048, T=512, D=1, H=50, OUT=3, fp32.
//
// R10: NW=4 (1 wave/SIMD), 4 tiles/wave. History:
//  R1-R4 (582..539us): VALU-bound lane=unit designs (R1 AGPR-shuttle
//     inflation confirmed at the CORRECT 2.4 GHz clock).
//  R5 381 / R6 291 / R7 345 / R8 268.6 / R9 269 us dispatch: MFMA designs.
//  R9's null result (removed trans + reads -> 0 change) + 2.4 GHz re-audit:
//  iter = 1260 cyc, VALU busy 315/SIMD, MFMA 105 -> ~70% is lockstep
//  serialization: 26-read LDS burst, uneven 4/3/3/3 waves/SIMD straggler,
//  13-wave barrier. Work-trimming can't fix structure.
//
// R10 structure:
//  * NW=4 waves, each owns 4 gate-tiles (16 tiles, 64 unit slots, 50 real).
//    1 wave/SIMD: zero VALU stacking, balanced barrier, read burst 26->8.
//  * Unit permutation: tile tau=4w+m, row R -> (gate=R&3, unit=16w+4(R>>2)+m).
//    Lane (hi,bcol) updates units 16w+4hi+{0..3} = CONSECUTIVE -> h-write
//    is ONE ds_write_b64 (4 packed fp16) per lane; 4 write instrs/block.
//  * Pad units (50..63): wih/bs zeroed -> v=0 -> c stays 0 -> h=0 exactly;
//    B1 read unmasked (pad slots hold written zeros).
//  * Per iter/wave: 2 b128 reads, 16 MFMAs (8 indep 2-chains), 4 merged-rcp
//    updates (indep chains), 1 b64 write, 1 barrier(4 waves).
//  * fp16 2-term W (hi + 2^-11*lo), fp16 h (R8-verified, absmax 4.9e-4).
// Layout conventions (R5-R9 verified):
//  A: row=lane&15, k=8*(lane>>4)+e (+32/K-step); B: col=lane&15, same k;
//  D: col=lane&15, row=4*(lane>>4)+reg.

#define BB 2048
#define TT 512
#define HH 50
#define NB 16            // batches per block (= MFMA cols)
#define NW 4             // waves; 4 tiles each -> 64 unit slots (50 real)
#define XP 513           // xs row stride (floats)
#define HS 72            // hf unit-slot stride per batch row (u16; 144B)
#define LO_SCALE  2048.0f            // 2^11
#define LO_ISCALE 0.00048828125f     // 2^-11
#define L1 -1.4426950408889634f      // -log2(e)
#define L2 -2.8853900817779268f      // -2*log2(e)

typedef __attribute__((ext_vector_type(4))) float        f32x4;
typedef __attribute__((ext_vector_type(8))) _Float16     f16x8;
typedef __attribute__((ext_vector_type(2))) unsigned int u32x2;

__global__ __launch_bounds__(NW * 64)
__attribute__((amdgpu_waves_per_eu(1, 1)))
void lstm_r10_kernel(const float* __restrict__ x,
                     const float* __restrict__ W_ih,
                     const float* __restrict__ W_hh,
                     const float* __restrict__ b_ih,
                     const float* __restrict__ b_hh,
                     const float* __restrict__ fc_w,
                     const float* __restrict__ fc_b,
                     float* __restrict__ out) {
    __shared__ float xs[NB * XP];                           // 32.8 KB
    __shared__ __align__(16) unsigned short hf[2][NB][HS];  // 4.6 KB (fp16 h)
    __shared__ float hfin[NB][64];                          // 4 KB

    const int tid  = threadIdx.x;
    const int w    = tid >> 6;          // wave id, 0..3 (tiles 4w..4w+3)
    const int lane = tid & 63;
    const int hi   = lane >> 4;
    const int bcol = lane & 15;         // batch column
    const int b0   = blockIdx.x * NB;

    // ---- stage x rows (coalesced) ----
    for (int idx = tid; idx < NB * TT; idx += NW * 64) {
        xs[(idx >> 9) * XP + (idx & 511)] = x[(b0 + (idx >> 9)) * TT + (idx & 511)];
    }
    // ---- zero h state (both buffers incl. pad slots) ----
    for (int idx = tid; idx < (int)(sizeof(hf) / 4); idx += NW * 64) {
        ((unsigned*)hf)[idx] = 0;
    }

    // ---- A-fragments: 4 tiles, permuted rows, fp16 hi/lo ----
    // A-side lane supplies tile-row R = lane&15: gate = R&3, unit = 16w+4(R>>2)+m
    const int ga = bcol & 3;
    const int qa = bcol >> 2;
    f16x8 Ah[4][2], Al[4][2];
    #pragma unroll
    for (int m = 0; m < 4; ++m) {
        const int ua = 16 * w + 4 * qa + m;
        const bool ok = (ua < HH);
        #pragma unroll
        for (int s = 0; s < 2; ++s) {
            f16x8 vh, vl;
            #pragma unroll
            for (int e = 0; e < 8; ++e) {
                const int k = 32 * s + 8 * hi + e;
                const float wv = (ok && k < HH) ? W_hh[(ga * HH + ua) * HH + k] : 0.0f;
                const _Float16 whv = (_Float16)wv;                       // RTN
                vh[e] = whv;
                vl[e] = (_Float16)((wv - (float)whv) * LO_SCALE);
            }
            Ah[m][s] = vh;
            Al[m][s] = vl;
        }
    }

    // ---- update params: lane (hi,bcol) owns units 16w+4hi+m ----
    float wih_[4][4], bs_[4][4];
    #pragma unroll
    for (int m = 0; m < 4; ++m) {
        const int u = 16 * w + 4 * hi + m;
        const bool ok = (u < HH);
        #pragma unroll
        for (int r = 0; r < 4; ++r) {       // gate r rows: r*HH + u
            wih_[m][r] = ok ? W_ih[r * HH + u] : 0.0f;
            bs_[m][r]  = ok ? (b_ih[r * HH + u] + b_hh[r * HH + u]) : 0.0f;
        }
    }

    // ---- LDS bases (u16 units). buf stride = NB*HS = 1152 ----
    const unsigned short* rb = &hf[0][bcol][8 * hi];            // B-frag reads
    unsigned short*       wb = &hf[0][bcol][16 * w + 4 * hi];   // b64 h write

    float c0 = 0, c1 = 0, c2 = 0, c3 = 0;
    float h0 = 0, h1 = 0, h2 = 0, h3 = 0;

    __syncthreads();

    // one (unit,batch) update: merged-rcp LSTM cell (R9-verified algebra)
#define UPDATE(A, B2, CC, HO) { \
        const float v0 = fmaf((B2)[0], LO_ISCALE, (A)[0]); \
        const float v1 = fmaf((B2)[1], LO_ISCALE, (A)[1]); \
        const float v2 = fmaf((B2)[2], LO_ISCALE, (A)[2]); \
        const float v3 = fmaf((B2)[3], LO_ISCALE, (A)[3]); \
        const float E1 = __builtin_amdgcn_exp2f(L1 * v0);   /* i */ \
        const float E2 = __builtin_amdgcn_exp2f(L1 * v1);   /* f */ \
        const float G  = __builtin_amdgcn_exp2f(L2 * v2);   /* g */ \
        const float E4 = __builtin_amdgcn_exp2f(L1 * v3);   /* o */ \
        const float P1 = 1.0f + E1, P2 = 1.0f + E2; \
        const float PG = 1.0f + G,  P4 = 1.0f + E4; \
        const float MG = 1.0f - G; \
        const float N  = fmaf((CC) * P1, PG, MG * P2); \
        const float D  = (P1 * P2) * PG; \
        CC = N * __builtin_amdgcn_rcpf(D); \
        const float C5 = __builtin_amdgcn_exp2f(L2 * (CC)); \
        const float Q  = (1.0f + C5) * P4; \
        HO = (1.0f - C5) * __builtin_amdgcn_rcpf(Q); }

    // One step: read buf CB, write buf 1-CB, one barrier.
#define STEP(CB, T) { \
        const f16x8 B0 = *(const f16x8*)(rb + (CB) * 1152); \
        const f16x8 B1 = *(const f16x8*)(rb + (CB) * 1152 + 32); \
        const float xv = xs[bcol * XP + (T)]; \
        f32x4 a0, a1, a2, a3, e0, e1, e2, e3; \
        _Pragma("unroll") \
        for (int r = 0; r < 4; ++r) { \
            a0[r] = fmaf(xv, wih_[0][r], bs_[0][r]); e0[r] = 0.0f; \
            a1[r] = fmaf(xv, wih_[1][r], bs_[1][r]); e1[r] = 0.0f; \
            a2[r] = fmaf(xv, wih_[2][r], bs_[2][r]); e2[r] = 0.0f; \
            a3[r] = fmaf(xv, wih_[3][r], bs_[3][r]); e3[r] = 0.0f; } \
        a0 = __builtin_amdgcn_mfma_f32_16x16x32_f16(Ah[0][0], B0, a0, 0, 0, 0); \
        a1 = __builtin_amdgcn_mfma_f32_16x16x32_f16(Ah[1][0], B0, a1, 0, 0, 0); \
        a2 = __builtin_amdgcn_mfma_f32_16x16x32_f16(Ah[2][0], B0, a2, 0, 0, 0); \
        a3 = __builtin_amdgcn_mfma_f32_16x16x32_f16(Ah[3][0], B0, a3, 0, 0, 0); \
        e0 = __builtin_amdgcn_mfma_f32_16x16x32_f16(Al[0][0], B0, e0, 0, 0, 0); \
        e1 = __builtin_amdgcn_mfma_f32_16x16x32_f16(Al[1][0], B0, e1, 0, 0, 0); \
        e2 = __builtin_amdgcn_mfma_f32_16x16x32_f16(Al[2][0], B0, e2, 0, 0, 0); \
        e3 = __builtin_amdgcn_mfma_f32_16x16x32_f16(Al[3][0], B0, e3, 0, 0, 0); \
        a0 = __builtin_amdgcn_mfma_f32_16x16x32_f16(Ah[0][1], B1, a0, 0, 0, 0); \
        a1 = __builtin_amdgcn_mfma_f32_16x16x32_f16(Ah[1][1], B1, a1, 0, 0, 0); \
        a2 = __builtin_amdgcn_mfma_f32_16x16x32_f16(Ah[2][1], B1, a2, 0, 0, 0); \
        a3 = __builtin_amdgcn_mfma_f32_16x16x32_f16(Ah[3][1], B1, a3, 0, 0, 0); \
        e0 = __builtin_amdgcn_mfma_f32_16x16x32_f16(Al[0][1], B1, e0, 0, 0, 0); \
        e1 = __builtin_amdgcn_mfma_f32_16x16x32_f16(Al[1][1], B1, e1, 0, 0, 0); \
        e2 = __builtin_amdgcn_mfma_f32_16x16x32_f16(Al[2][1], B1, e2, 0, 0, 0); \
        e3 = __builtin_amdgcn_mfma_f32_16x16x32_f16(Al[3][1], B1, e3, 0, 0, 0); \
        UPDATE(a0, e0, c0, h0) \
        UPDATE(a1, e1, c1, h1) \
        UPDATE(a2, e2, c2, h2) \
        UPDATE(a3, e3, c3, h3) \
        const unsigned short q0 = __builtin_bit_cast(unsigned short, (_Float16)h0); \
        const unsigned short q1 = __builtin_bit_cast(unsigned short, (_Float16)h1); \
        const unsigned short q2 = __builtin_bit_cast(unsigned short, (_Float16)h2); \
        const unsigned short q3 = __builtin_bit_cast(unsigned short, (_Float16)h3); \
        u32x2 P; \
        P[0] = (unsigned)q0 | ((unsigned)q1 << 16); \
        P[1] = (unsigned)q2 | ((unsigned)q3 << 16); \
        *(u32x2*)(wb + (1 - (CB)) * 1152) = P; \
        __syncthreads(); }

    #pragma unroll 1
    for (int t = 0; t < TT; t += 2) {
        STEP(0, t)
        STEP(1, t + 1)
    }
#undef STEP
#undef UPDATE

    // ---- epilogue: h_T dot fc_w (once) ----
    hfin[bcol][16 * w + 4 * hi + 0] = h0;
    hfin[bcol][16 * w + 4 * hi + 1] = h1;
    hfin[bcol][16 * w + 4 * hi + 2] = h2;
    hfin[bcol][16 * w + 4 * hi + 3] = h3;
    __syncthreads();
    if (tid < NB * 3) {
        const int b = tid / 3, o = tid % 3;
        float s = fc_b[o];
        for (int uu = 0; uu < HH; ++uu)
            s = fmaf(hfin[b][uu], fc_w[o * HH + uu], s);
        out[(b0 + b) * 3 + o] = s;
    }
}

extern "C" void kernel_launch(void* const* d_in, const int* in_sizes, int n_in,
                              void* d_out, int out_size, void* d_ws, size_t ws_size,
                              hipStream_t stream) {
    const float* x    = (const float*)d_in[0];
    const float* W_ih = (const float*)d_in[1];
    const float* W_hh = (const float*)d_in[2];
    const float* b_ih = (const float*)d_in[3];
    const float* b_hh = (const float*)d_in[4];
    const float* fc_w = (const float*)d_in[5];
    const float* fc_b = (const float*)d_in[6];
    float* out = (float*)d_out;

    dim3 grid(BB / NB);      // 128 blocks
    dim3 block(NW * 64);     // 256 threads = 4 waves (1 per SIMD)
    lstm_r10_kernel<<<grid, block, 0, stream>>>(x, W_ih, W_hh, b_ih, b_hh,
                                                fc_w, fc_b, out);
}

// Round 11
// 262.790 us; speedup vs baseline: 1.3831x; 1.3831x over previous
//
#include <hip/hip_runtime.h>

// LSTM: B=2048, T=512, D=1, H=50, OUT=3, fp32.
//
// R12 = R11 + h-write guard (bugfix). History (dispatch us):
//  R1-R4 582..539: VALU-bound lane=unit. R5 381. R6 291 (NW13 fused).
//  R7 345 (NW8). R8 268.6 (fp16 2-term). R9 269 (trim: null). R10 316
//  (NW4: latency exposed). R11 FAIL absmax 4.15e-2: with NW=16 the
//  h-write mapping unit=4w+hi covers slots 0..63 -> wave15 pad lanes
//  clobbered aug slots 61/62/63 (x, bias) with h=0 every step.
//
// R12: guard h-writes to units < 50. Slots 50..60 stay zero (init);
// 61/62/63 have exactly one writer (xwriter / prologue). Rest = R11:
//  * K-augmentation: B1 pad slots carry slot62=1.0 (bias hi/lo in A),
//    slot63=x_hi, slot61=x_lo' (x = xh + 2^-11 xl'). Per-step gate-init
//    VALU = 0; acc chains start from persistent zero4.
//  * L-prescale (-log2e / -2log2e) folded into A hi/lo -> E=exp2(v).
//  * NW=16: exactly 4 waves/SIMD (balanced stacking + barrier); waves
//    13-15 compute pad only (discarded) but keep SIMDs symmetric.
// Layout conventions (R5-R10 verified): A row=lane&15 (permuted:
// gate=R&3, unit=4w+(R>>2)), k=8*(lane>>4)+e (+32/K-step); B col=lane&15,
// same k; D col=lane&15, row=4*(lane>>4)+reg. fp16 2-term W; fp16 h.
// Merged-rcp cell (R9-verified algebra).

#define BB 2048
#define TT 512
#define HH 50
#define NB 16            // batches per block (= MFMA cols)
#define NW 16            // waves = tiles; 64 unit slots (50 real)
#define XP 513           // xs row stride (floats)
#define HS 72            // hf unit-slot stride per batch row (u16; 144B)
#define LO_SCALE  2048.0f            // 2^11
#define LO_ISCALE 0.00048828125f     // 2^-11
#define L1 -1.4426950408889634f      // -log2(e)
#define L2 -2.8853900817779268f      // -2*log2(e)

typedef __attribute__((ext_vector_type(4))) float    f32x4;
typedef __attribute__((ext_vector_type(8))) _Float16 f16x8;

__global__ __launch_bounds__(NW * 64)
void lstm_r12_kernel(const float* __restrict__ x,
                     const float* __restrict__ W_ih,
                     const float* __restrict__ W_hh,
                     const float* __restrict__ b_ih,
                     const float* __restrict__ b_hh,
                     const float* __restrict__ fc_w,
                     const float* __restrict__ fc_b,
                     float* __restrict__ out) {
    __shared__ float xs[NB * XP];                           // 32.8 KB
    __shared__ __align__(16) unsigned short hf[2][NB][HS];  // 4.6 KB (fp16 h + aug)
    __shared__ float hfin[NB][64];                          // 4 KB

    const int tid  = threadIdx.x;
    const int w    = tid >> 6;          // wave id = tile id, 0..15
    const int lane = tid & 63;
    const int hi   = lane >> 4;
    const int bcol = lane & 15;         // batch column
    const int b0   = blockIdx.x * NB;

    // ---- stage x rows (coalesced) + zero pad col 512 ----
    for (int idx = tid; idx < NB * TT; idx += NW * 64) {
        xs[(idx >> 9) * XP + (idx & 511)] = x[(b0 + (idx >> 9)) * TT + (idx & 511)];
    }
    if (tid < NB) xs[tid * XP + 512] = 0.0f;
    // ---- zero h state (both buffers incl. all pad/aug slots) ----
    for (int idx = tid; idx < (int)(sizeof(hf) / 4); idx += NW * 64) {
        ((unsigned*)hf)[idx] = 0;
    }

    // ---- A-fragments: permuted rows, L-prescaled fp16 hi/lo, augmented ----
    // Lane supplies A row R = lane&15: gate ga = R&3, unit ua = 4w+(R>>2).
    // k-columns: [0,50) = L*W_hh hi/lo; 61: Al=fp16(L*W_ih) (pairs x_lo');
    // 62 (B=1.0): bias hi/lo; 63 (B=x_hi): L*W_ih hi/lo; rest 0.
    const int ga = bcol & 3;
    const int ua = 4 * w + (bcol >> 2);
    const bool ok = (ua < HH);
    const float Lg = (ga == 2) ? L2 : L1;
    f16x8 Ah0, Ah1, Al0, Al1;
    #pragma unroll
    for (int s = 0; s < 2; ++s) {
        #pragma unroll
        for (int e = 0; e < 8; ++e) {
            const int k = 32 * s + 8 * hi + e;
            _Float16 ah = (_Float16)0.0f, al = (_Float16)0.0f;
            if (ok) {
                if (k < HH) {
                    const float wv = Lg * W_hh[(ga * HH + ua) * HH + k];
                    ah = (_Float16)wv;
                    al = (_Float16)((wv - (float)ah) * LO_SCALE);
                } else if (k == 61) {
                    // pairs with B=x_lo' (pre-scaled 2^11): term 2^-11*wh*xl'
                    al = (_Float16)(Lg * W_ih[ga * HH + ua]);
                } else if (k == 62) {
                    // pairs with B=1.0: bias hi/lo
                    const float bv = Lg * (b_ih[ga * HH + ua] + b_hh[ga * HH + ua]);
                    ah = (_Float16)bv;
                    al = (_Float16)((bv - (float)ah) * LO_SCALE);
                } else if (k == 63) {
                    // pairs with B=x_hi
                    const float wv = Lg * W_ih[ga * HH + ua];
                    ah = (_Float16)wv;
                    al = (_Float16)((wv - (float)ah) * LO_SCALE);
                }
            }
            if (s == 0) { Ah0[e] = ah; Al0[e] = al; }
            else        { Ah1[e] = ah; Al1[e] = al; }
        }
    }

    // ---- LDS pointers (u16 units). buf stride = NB*HS = 1152 ----
    const unsigned short* rb  = &hf[0][bcol][8 * hi];    // B-frag reads
    unsigned short*       wb  = &hf[0][bcol][4 * w + hi];// h write (unit slot)
    unsigned short*       xwb = &hf[0][bcol][0];         // aug writes (wave0/hi3)
    const bool xwriter = (w == 0) && (hi == 3);
    const bool hwriter = (4 * w + hi) < HH;   // BUGFIX: pad units must not
                                              // write (slots 50..63 incl. aug)

    __syncthreads();   // zero-init complete

    // ---- prologue aug writes: 1.0 -> slot62 (both bufs); x(0) -> buf0 ----
    if (xwriter) {
        const unsigned short one_h = __builtin_bit_cast(unsigned short, (_Float16)1.0f);
        xwb[62] = one_h;
        xwb[1152 + 62] = one_h;
        const float x0 = xs[bcol * XP + 0];
        const _Float16 xh = (_Float16)x0;
        const _Float16 xl = (_Float16)((x0 - (float)xh) * LO_SCALE);
        xwb[63] = __builtin_bit_cast(unsigned short, xh);
        xwb[61] = __builtin_bit_cast(unsigned short, xl);
    }

    float c = 0.0f, hcur = 0.0f;
    const f32x4 zero4 = {0.0f, 0.0f, 0.0f, 0.0f};

    __syncthreads();

    // One step: read buf CB (h(t-1) + aug x(t)), write buf 1-CB, one barrier.
#define STEP(CB, T) { \
        const f16x8 B0 = *(const f16x8*)(rb + (CB) * 1152); \
        const f16x8 B1 = *(const f16x8*)(rb + (CB) * 1152 + 32); \
        f32x4 acc  = __builtin_amdgcn_mfma_f32_16x16x32_f16(Ah0, B0, zero4, 0, 0, 0); \
        f32x4 acc2 = __builtin_amdgcn_mfma_f32_16x16x32_f16(Al0, B0, zero4, 0, 0, 0); \
        acc  = __builtin_amdgcn_mfma_f32_16x16x32_f16(Ah1, B1, acc,  0, 0, 0); \
        acc2 = __builtin_amdgcn_mfma_f32_16x16x32_f16(Al1, B1, acc2, 0, 0, 0); \
        /* v = L*preact directly (prescaled rows) */ \
        const float v0 = fmaf(acc2[0], LO_ISCALE, acc[0]); \
        const float v1 = fmaf(acc2[1], LO_ISCALE, acc[1]); \
        const float v2 = fmaf(acc2[2], LO_ISCALE, acc[2]); \
        const float v3 = fmaf(acc2[3], LO_ISCALE, acc[3]); \
        const float E1 = __builtin_amdgcn_exp2f(v0);   /* i */ \
        const float E2 = __builtin_amdgcn_exp2f(v1);   /* f */ \
        const float G  = __builtin_amdgcn_exp2f(v2);   /* g */ \
        const float E4 = __builtin_amdgcn_exp2f(v3);   /* o */ \
        const float P1 = 1.0f + E1, P2 = 1.0f + E2; \
        const float PG = 1.0f + G,  P4 = 1.0f + E4; \
        const float MG = 1.0f - G; \
        const float N  = fmaf(c * P1, PG, MG * P2); \
        const float D  = (P1 * P2) * PG; \
        c = N * __builtin_amdgcn_rcpf(D); \
        const float C5 = __builtin_amdgcn_exp2f(L2 * c); \
        const float Q  = (1.0f + C5) * P4; \
        hcur = (1.0f - C5) * __builtin_amdgcn_rcpf(Q); \
        if (hwriter) \
            wb[(1 - (CB)) * 1152] = __builtin_bit_cast(unsigned short, (_Float16)hcur); \
        if (xwriter) { \
            const float xn = xs[bcol * XP + (T) + 1]; \
            const _Float16 xh = (_Float16)xn; \
            const _Float16 xl = (_Float16)((xn - (float)xh) * LO_SCALE); \
            xwb[(1 - (CB)) * 1152 + 63] = __builtin_bit_cast(unsigned short, xh); \
            xwb[(1 - (CB)) * 1152 + 61] = __builtin_bit_cast(unsigned short, xl); \
        } \
        __syncthreads(); }

    #pragma unroll 1
    for (int t = 0; t < TT; t += 2) {
        STEP(0, t)
        STEP(1, t + 1)
    }
#undef STEP

    // ---- epilogue: h_T dot fc_w (once) ----
    hfin[bcol][4 * w + hi] = hcur;      // pad units hold 0, unused below
    __syncthreads();
    if (tid < NB * 3) {
        const int b = tid / 3, o = tid % 3;
        float s = fc_b[o];
        for (int uu = 0; uu < HH; ++uu)
            s = fmaf(hfin[b][uu], fc_w[o * HH + uu], s);
        out[(b0 + b) * 3 + o] = s;
    }
}

extern "C" void kernel_launch(void* const* d_in, const int* in_sizes, int n_in,
                              void* d_out, int out_size, void* d_ws, size_t ws_size,
                              hipStream_t stream) {
    const float* x    = (const float*)d_in[0];
    const float* W_ih = (const float*)d_in[1];
    const float* W_hh = (const float*)d_in[2];
    const float* b_ih = (const float*)d_in[3];
    const float* b_hh = (const float*)d_in[4];
    const float* fc_w = (const float*)d_in[5];
    const float* fc_b = (const float*)d_in[6];
    float* out = (float*)d_out;

    dim3 grid(BB / NB);      // 128 blocks
    dim3 block(NW * 64);     // 1024 threads = 16 waves (4 per SIMD)
    lstm_r12_kernel<<<grid, block, 0, stream>>>(x, W_ih, W_hh, b_ih, b_hh,
                                                fc_w, fc_b, out);
}